// Round 6
// baseline (333.326 us; speedup 1.0000x reference)
//
#include <hip/hip_runtime.h>

#define HH 352
#define WW 1216
#define NB 4
#define HWSZ (HH * WW)      // 428032 pixels per plane
#define WQ 304              // quads per row
#define NQ (NB * HH * WQ)   // softmax thread-quads
#define PPR 152             // pair-units (8px) per row
#define NP (NB * HH * PPR)  // 214016 prop threads -> 836 blocks exactly

typedef _Float16 half8 __attribute__((ext_vector_type(8)));

// kern ws layout: [NB][9][HWSZ][2] fp16, innermost pair = (k1,k2) premultiplied
// by fuse. half8 covers 4 px x 2 kernels.

// ---------------------------------------------------------------------------
// Softmax(9ch) both guided tensors, premultiplied by fuse, interleaved fp16.
// 18 plane loads hoisted; ~5.4 TB/s effective (near mixed-stream ceiling).
// ---------------------------------------------------------------------------
__global__ __launch_bounds__(256, 2) void softmax_premul_kernel(
    const float* __restrict__ g1, const float* __restrict__ g2,
    const float* __restrict__ fuse, _Float16* __restrict__ ko) {
    int q = blockIdx.x * 256 + threadIdx.x;
    if (q >= NQ) return;
    int b   = q / (HH * WQ);
    int rem = q - b * (HH * WQ);
    long gbase = (long)b * 9 * HWSZ + (long)rem * 4;
    long fbase = (long)b * 2 * HWSZ + (long)rem * 4;

    float4 t[18];
#pragma unroll
    for (int k = 0; k < 9; k++) t[k]     = *(const float4*)(g1 + gbase + (long)k * HWSZ);
#pragma unroll
    for (int k = 0; k < 9; k++) t[9 + k] = *(const float4*)(g2 + gbase + (long)k * HWSZ);
    float4 f1 = *(const float4*)(fuse + fbase);
    float4 f2 = *(const float4*)(fuse + fbase + HWSZ);

    float s1[4] = {0.f, 0.f, 0.f, 0.f}, s2[4] = {0.f, 0.f, 0.f, 0.f};
#pragma unroll
    for (int k = 0; k < 9; k++) {
        t[k].x = __expf(t[k].x); s1[0] += t[k].x;
        t[k].y = __expf(t[k].y); s1[1] += t[k].y;
        t[k].z = __expf(t[k].z); s1[2] += t[k].z;
        t[k].w = __expf(t[k].w); s1[3] += t[k].w;
    }
#pragma unroll
    for (int k = 9; k < 18; k++) {
        t[k].x = __expf(t[k].x); s2[0] += t[k].x;
        t[k].y = __expf(t[k].y); s2[1] += t[k].y;
        t[k].z = __expf(t[k].z); s2[2] += t[k].z;
        t[k].w = __expf(t[k].w); s2[3] += t[k].w;
    }
    float r1[4], r2[4];
    r1[0] = f1.x / s1[0]; r1[1] = f1.y / s1[1]; r1[2] = f1.z / s1[2]; r1[3] = f1.w / s1[3];
    r2[0] = f2.x / s2[0]; r2[1] = f2.y / s2[1]; r2[2] = f2.z / s2[2]; r2[3] = f2.w / s2[3];

    long obase = ((long)b * 9 * HWSZ + (long)rem * 4) * 2;
#pragma unroll
    for (int k = 0; k < 9; k++) {
        half8 o;
        o[0] = (_Float16)(t[k].x * r1[0]); o[1] = (_Float16)(t[9 + k].x * r2[0]);
        o[2] = (_Float16)(t[k].y * r1[1]); o[3] = (_Float16)(t[9 + k].y * r2[1]);
        o[4] = (_Float16)(t[k].z * r1[2]); o[5] = (_Float16)(t[9 + k].z * r2[2]);
        o[6] = (_Float16)(t[k].w * r1[3]); o[7] = (_Float16)(t[9 + k].w * r2[3]);
        *(half8*)(ko + obase + (long)k * HWSZ * 2) = o;
    }
}

// ---------------------------------------------------------------------------
// Propagation step, barrier-free, 8 px per thread. 18 kern half8 loads + 20 x
// float4 loads all hoisted and independent (max loads-in-flight), then 288
// FMAs. Zero-padding via clamped addresses + {0,1} masks (branch-free).
// x coverage per thread: rows h-2..h+2, cols w0-4..w0+11 (4 aligned float4),
// taps use cols w0-2..w0+9 only.
// ---------------------------------------------------------------------------
__global__ __launch_bounds__(256, 2) void prop8_kernel(
    const _Float16* __restrict__ kk,
    const float* __restrict__ xin, float* __restrict__ xout) {
    int p = blockIdx.x * 256 + threadIdx.x;   // grid exact: NP = 836*256
    int b   = p / (HH * PPR);
    int rem = p - b * (HH * PPR);
    int h   = rem / PPR;
    int pq  = rem - h * PPR;
    int w0  = pq * 8;

    const float* xb = xin + (long)b * HWSZ;
    long kbase = ((long)b * 9 * HWSZ + (long)h * WW + w0) * 2;

    // ---- 18 kern loads (16B each), hoisted ----
    half8 kv[18];
#pragma unroll
    for (int k = 0; k < 9; k++) {
        kv[2 * k]     = *(const half8*)(kk + kbase + (long)k * HWSZ * 2);
        kv[2 * k + 1] = *(const half8*)(kk + kbase + (long)k * HWSZ * 2 + 8);
    }

    // ---- 20 x loads (rows clamped, cols clamped, masked after) ----
    float ml = (w0 > 0) ? 1.f : 0.f;          // cols w0-4..w0-1 validity
    float mr = (w0 + 8 < WW) ? 1.f : 0.f;     // cols w0+8..w0+11 validity
    int c0 = (w0 > 0) ? (w0 - 4) : 0;
    int c3 = (w0 + 8 < WW) ? (w0 + 8) : (WW - 4);

    float xf[5][16];
#pragma unroll
    for (int r = 0; r < 5; r++) {
        int hh = h - 2 + r;
        int hc = hh < 0 ? 0 : (hh >= HH ? HH - 1 : hh);
        float mv = (hh >= 0 && hh < HH) ? 1.f : 0.f;
        const float* rp = xb + (long)hc * WW;
        float4 v0 = *(const float4*)(rp + c0);
        float4 v1 = *(const float4*)(rp + w0);
        float4 v2 = *(const float4*)(rp + w0 + 4);
        float4 v3 = *(const float4*)(rp + c3);
        float mlv = mv * ml, mrv = mv * mr;
        xf[r][0]  = v0.x * mlv; xf[r][1]  = v0.y * mlv;
        xf[r][2]  = v0.z * mlv; xf[r][3]  = v0.w * mlv;
        xf[r][4]  = v1.x * mv;  xf[r][5]  = v1.y * mv;
        xf[r][6]  = v1.z * mv;  xf[r][7]  = v1.w * mv;
        xf[r][8]  = v2.x * mv;  xf[r][9]  = v2.y * mv;
        xf[r][10] = v2.z * mv;  xf[r][11] = v2.w * mv;
        xf[r][12] = v3.x * mrv; xf[r][13] = v3.y * mrv;
        xf[r][14] = v3.z * mrv; xf[r][15] = v3.w * mrv;
    }

    // ---- 288 FMAs: px j (=4q+jj), dil1 rows 1..3 / dil2 rows 0,2,4 ----
    float o[8] = {0.f, 0.f, 0.f, 0.f, 0.f, 0.f, 0.f, 0.f};
#pragma unroll
    for (int ky = 0; ky < 3; ky++) {
#pragma unroll
        for (int kx = 0; kx < 3; kx++) {
            int k = ky * 3 + kx;
#pragma unroll
            for (int qd = 0; qd < 2; qd++) {
#pragma unroll
                for (int jj = 0; jj < 4; jj++) {
                    int j = 4 * qd + jj;
                    // dil1: col w0+j+(kx-1) -> xf col (j+3+kx); row h+(ky-1) -> r=ky+1
                    o[j] = fmaf((float)kv[2 * k + qd][2 * jj],     xf[ky + 1][j + 3 + kx],     o[j]);
                    // dil2: col w0+j+2(kx-1) -> xf col (j+2+2kx); row h+2(ky-1) -> r=2ky
                    o[j] = fmaf((float)kv[2 * k + qd][2 * jj + 1], xf[2 * ky][j + 2 + 2 * kx], o[j]);
                }
            }
        }
    }

    float* op = xout + (long)b * HWSZ + (long)h * WW + w0;
    *(float4*)op       = make_float4(o[0], o[1], o[2], o[3]);
    *(float4*)(op + 4) = make_float4(o[4], o[5], o[6], o[7]);
}

extern "C" void kernel_launch(void* const* d_in, const int* in_sizes, int n_in,
                              void* d_out, int out_size, void* d_ws, size_t ws_size,
                              hipStream_t stream) {
    const float* g1   = (const float*)d_in[0];
    const float* g2   = (const float*)d_in[1];
    const float* fuse = (const float*)d_in[2];
    const float* x    = (const float*)d_in[3];
    float* out = (float*)d_out;

    _Float16* kk = (_Float16*)d_ws;
    float* bufA  = (float*)(kk + (size_t)NB * 9 * HWSZ * 2);

    int sm_blocks = (NQ + 255) / 256;
    softmax_premul_kernel<<<sm_blocks, 256, 0, stream>>>(g1, g2, fuse, kk);

    int pr_blocks = NP / 256;   // 836 exactly
    prop8_kernel<<<pr_blocks, 256, 0, stream>>>(kk, x,    bufA);
    prop8_kernel<<<pr_blocks, 256, 0, stream>>>(kk, bufA, out);
    prop8_kernel<<<pr_blocks, 256, 0, stream>>>(kk, out,  bufA);
    prop8_kernel<<<pr_blocks, 256, 0, stream>>>(kk, bufA, out);
    prop8_kernel<<<pr_blocks, 256, 0, stream>>>(kk, out,  bufA);
    prop8_kernel<<<pr_blocks, 256, 0, stream>>>(kk, bufA, out);
    prop8_kernel<<<pr_blocks, 256, 0, stream>>>(kk, out,  bufA);
    prop8_kernel<<<pr_blocks, 256, 0, stream>>>(kk, bufA, out);
}

// Round 8
// 246.508 us; speedup vs baseline: 1.3522x; 1.3522x over previous
//
#include <hip/hip_runtime.h>

#define HH 352
#define WW 1216
#define NB 4
#define HWSZ (HH * WW)      // 428032 pixels per plane
#define WQ 304              // quads per row
#define BHQ (HH * WQ)       // quads per batch
#define NQ (NB * BHQ)       // 428032 total quads

typedef _Float16 half4 __attribute__((ext_vector_type(4)));
typedef _Float16 half8 __attribute__((ext_vector_type(8)));

// kern ws layout: [NB][9][HWSZ][2] fp16, pair = (k1,k2) premultiplied by fuse.
// Intermediate x buffers are fp16 (values <= ~8, err ~5e-4 rel; budget ok).

// ---------------------------------------------------------------------------
// Fused: softmax+premul for both guided tensors AND propagation step 1.
// The thread's own kern is in registers after the softmax phase, so step 1
// costs only the 15 predicated x0 row loads + 72 FMAs + one 8B fp16 store.
// t[18] is consumed into kv[9] before x loads begin (register reuse).
// ---------------------------------------------------------------------------
__global__ __launch_bounds__(256, 4) void softmax_prop1_kernel(
    const float* __restrict__ g1, const float* __restrict__ g2,
    const float* __restrict__ fuse, const float* __restrict__ x0,
    _Float16* __restrict__ kk, _Float16* __restrict__ x1) {
    int q = blockIdx.x * 256 + threadIdx.x;
    if (q >= NQ) return;
    int b   = q / BHQ;
    int rem = q - b * BHQ;
    int h   = rem / WQ;
    int wq  = rem - h * WQ;
    int w0  = wq * 4;
    long gbase = (long)b * 9 * HWSZ + (long)rem * 4;
    long fbase = (long)b * 2 * HWSZ + (long)rem * 4;

    // ---- softmax phase ----
    float4 t[18];
#pragma unroll
    for (int k = 0; k < 9; k++) t[k]     = *(const float4*)(g1 + gbase + (long)k * HWSZ);
#pragma unroll
    for (int k = 0; k < 9; k++) t[9 + k] = *(const float4*)(g2 + gbase + (long)k * HWSZ);
    float4 f1 = *(const float4*)(fuse + fbase);
    float4 f2 = *(const float4*)(fuse + fbase + HWSZ);

    float s1[4] = {0.f, 0.f, 0.f, 0.f}, s2[4] = {0.f, 0.f, 0.f, 0.f};
#pragma unroll
    for (int k = 0; k < 9; k++) {
        t[k].x = __expf(t[k].x); s1[0] += t[k].x;
        t[k].y = __expf(t[k].y); s1[1] += t[k].y;
        t[k].z = __expf(t[k].z); s1[2] += t[k].z;
        t[k].w = __expf(t[k].w); s1[3] += t[k].w;
    }
#pragma unroll
    for (int k = 9; k < 18; k++) {
        t[k].x = __expf(t[k].x); s2[0] += t[k].x;
        t[k].y = __expf(t[k].y); s2[1] += t[k].y;
        t[k].z = __expf(t[k].z); s2[2] += t[k].z;
        t[k].w = __expf(t[k].w); s2[3] += t[k].w;
    }
    float r1[4], r2[4];
    r1[0] = f1.x / s1[0]; r1[1] = f1.y / s1[1]; r1[2] = f1.z / s1[2]; r1[3] = f1.w / s1[3];
    r2[0] = f2.x / s2[0]; r2[1] = f2.y / s2[1]; r2[2] = f2.z / s2[2]; r2[3] = f2.w / s2[3];

    long obase = gbase * 2;
    half8 kv[9];
#pragma unroll
    for (int k = 0; k < 9; k++) {
        half8 o;
        o[0] = (_Float16)(t[k].x * r1[0]); o[1] = (_Float16)(t[9 + k].x * r2[0]);
        o[2] = (_Float16)(t[k].y * r1[1]); o[3] = (_Float16)(t[9 + k].y * r2[1]);
        o[4] = (_Float16)(t[k].z * r1[2]); o[5] = (_Float16)(t[9 + k].z * r2[2]);
        o[6] = (_Float16)(t[k].w * r1[3]); o[7] = (_Float16)(t[9 + k].w * r2[3]);
        kv[k] = o;
        *(half8*)(kk + obase + (long)k * HWSZ * 2) = o;
    }

    // ---- propagation step 1 (fp32 x0 -> fp16 x1) ----
    const float* xb = x0 + (long)b * HWSZ;
    float rb[5][8];
#pragma unroll
    for (int r = 0; r < 5; r++) {
        int hh = h - 2 + r;
        bool rv = (hh >= 0) && (hh < HH);
        const float* rp = xb + (long)hh * WW;
        float4 mid = rv ? *(const float4*)(rp + w0) : make_float4(0.f, 0.f, 0.f, 0.f);
        float2 lft = (rv && w0 > 0) ? *(const float2*)(rp + w0 - 2) : make_float2(0.f, 0.f);
        float2 rgt = (rv && (w0 + 5) < WW) ? *(const float2*)(rp + w0 + 4) : make_float2(0.f, 0.f);
        rb[r][0] = lft.x; rb[r][1] = lft.y;
        rb[r][2] = mid.x; rb[r][3] = mid.y; rb[r][4] = mid.z; rb[r][5] = mid.w;
        rb[r][6] = rgt.x; rb[r][7] = rgt.y;
    }
    float o[4] = {0.f, 0.f, 0.f, 0.f};
#pragma unroll
    for (int ky = 0; ky < 3; ky++)
#pragma unroll
        for (int kx = 0; kx < 3; kx++) {
            int k = ky * 3 + kx;
#pragma unroll
            for (int j = 0; j < 4; j++) {
                o[j] = fmaf((float)kv[k][2 * j],     rb[ky + 1][j + 1 + kx], o[j]);
                o[j] = fmaf((float)kv[k][2 * j + 1], rb[2 * ky][j + 2 * kx], o[j]);
            }
        }
    half4 xo;
    xo[0] = (_Float16)o[0]; xo[1] = (_Float16)o[1];
    xo[2] = (_Float16)o[2]; xo[3] = (_Float16)o[3];
    *(half4*)(x1 + (long)b * HWSZ + (long)rem * 4) = xo;
}

// ---------------------------------------------------------------------------
// Propagation step, 2D-tiled (R4 structure): tile 64 quads x 4 rows, x staged
// through LDS as fp32 (converted from fp16 global on stage). OUT16 selects
// fp16 (intermediate) vs fp32 (final d_out) store.
// ---------------------------------------------------------------------------
#define TW 64
#define TH 4
#define LW (TW + 2)
#define LROWS (TH + 4)
#define TILES_W 5           // ceil(304/64); last tile ragged (48/64 active)
#define TILES_H (HH / TH)   // 88

template <int OUT16>
__global__ __launch_bounds__(256, 4) void prop_kernel(
    const _Float16* __restrict__ kk,
    const _Float16* __restrict__ xin, void* __restrict__ xout_) {
    __shared__ float xs[LROWS][LW * 4];

    int tid = threadIdx.x;
    int bidx = blockIdx.x;
    int tX = bidx % TILES_W;
    int r1 = bidx / TILES_W;
    int tY = r1 % TILES_H;
    int b  = r1 / TILES_H;
    int q0 = tX * TW;
    int h0 = tY * TH;

    const _Float16* xb = xin + (long)b * HWSZ;

    // ---- stage x tile + halo into LDS (fp16 global -> fp32 LDS) ----
#pragma unroll
    for (int i = tid; i < LROWS * LW; i += 256) {
        int row = i / LW;
        int qc  = i - row * LW;
        int h   = h0 - 2 + row;
        int qg  = q0 - 1 + qc;
        float4 v = make_float4(0.f, 0.f, 0.f, 0.f);
        if (h >= 0 && h < HH && qg >= 0 && qg < WQ) {
            half4 hv = *(const half4*)(xb + (long)h * WW + qg * 4);
            v = make_float4((float)hv[0], (float)hv[1], (float)hv[2], (float)hv[3]);
        }
        *(float4*)&xs[row][qc * 4] = v;
    }
    __syncthreads();

    int tx = tid & (TW - 1);
    int ty = tid >> 6;
    int qa = q0 + tx;
    if (qa >= WQ) return;   // ragged tail (after barrier)

    int h = h0 + ty;
    long p0 = (long)h * WW + qa * 4;
    long kbase = ((long)b * 9 * HWSZ + p0) * 2;

    half8 kv[9];
#pragma unroll
    for (int k = 0; k < 9; k++)
        kv[k] = *(const half8*)(kk + kbase + (long)k * HWSZ * 2);

    float rb[5][8];
#pragma unroll
    for (int r = 0; r < 5; r++) {
        const float* p = &xs[ty + r][4 * tx + 2];
        float2 a = *(const float2*)(p);
        float4 m = *(const float4*)(p + 2);
        float2 z = *(const float2*)(p + 6);
        rb[r][0] = a.x; rb[r][1] = a.y;
        rb[r][2] = m.x; rb[r][3] = m.y; rb[r][4] = m.z; rb[r][5] = m.w;
        rb[r][6] = z.x; rb[r][7] = z.y;
    }

    float o[4] = {0.f, 0.f, 0.f, 0.f};
#pragma unroll
    for (int ky = 0; ky < 3; ky++)
#pragma unroll
        for (int kx = 0; kx < 3; kx++) {
            int k = ky * 3 + kx;
#pragma unroll
            for (int j = 0; j < 4; j++) {
                o[j] = fmaf((float)kv[k][2 * j],     rb[ky + 1][j + 1 + kx], o[j]);
                o[j] = fmaf((float)kv[k][2 * j + 1], rb[2 * ky][j + 2 * kx], o[j]);
            }
        }

    if (OUT16) {
        half4 xo;
        xo[0] = (_Float16)o[0]; xo[1] = (_Float16)o[1];
        xo[2] = (_Float16)o[2]; xo[3] = (_Float16)o[3];
        *(half4*)((_Float16*)xout_ + (long)b * HWSZ + p0) = xo;
    } else {
        *(float4*)((float*)xout_ + (long)b * HWSZ + p0) =
            make_float4(o[0], o[1], o[2], o[3]);
    }
}

extern "C" void kernel_launch(void* const* d_in, const int* in_sizes, int n_in,
                              void* d_out, int out_size, void* d_ws, size_t ws_size,
                              hipStream_t stream) {
    const float* g1   = (const float*)d_in[0];
    const float* g2   = (const float*)d_in[1];
    const float* fuse = (const float*)d_in[2];
    const float* x    = (const float*)d_in[3];
    float* out = (float*)d_out;

    // ws: kk (61.6 MB) | bufA fp16 (3.4 MB) | bufB fp16 (3.4 MB)
    _Float16* kk   = (_Float16*)d_ws;
    _Float16* bufA = kk + (size_t)NB * 9 * HWSZ * 2;
    _Float16* bufB = bufA + (size_t)NB * HWSZ;

    int sm_blocks = (NQ + 255) / 256;   // 1672
    softmax_prop1_kernel<<<sm_blocks, 256, 0, stream>>>(g1, g2, fuse, x, kk, bufA);

    int pr_blocks = NB * TILES_H * TILES_W;   // 1760
    prop_kernel<1><<<pr_blocks, 256, 0, stream>>>(kk, bufA, bufB);  // step 2
    prop_kernel<1><<<pr_blocks, 256, 0, stream>>>(kk, bufB, bufA);  // step 3
    prop_kernel<1><<<pr_blocks, 256, 0, stream>>>(kk, bufA, bufB);  // step 4
    prop_kernel<1><<<pr_blocks, 256, 0, stream>>>(kk, bufB, bufA);  // step 5
    prop_kernel<1><<<pr_blocks, 256, 0, stream>>>(kk, bufA, bufB);  // step 6
    prop_kernel<1><<<pr_blocks, 256, 0, stream>>>(kk, bufB, bufA);  // step 7
    prop_kernel<0><<<pr_blocks, 256, 0, stream>>>(kk, bufA, out);   // step 8
}